// Round 9
// baseline (198.770 us; speedup 1.0000x reference)
//
#include <hip/hip_runtime.h>
#include <math.h>

// SpiralNet bf16-MFMA v9: sustained-concurrency + L1-bypass experiment.
// Model: big layers move 1.2M 128B lines; sustained ~26 line-misses/CU -> either
// software duty-cycle (fenced batches idle during MFMA phase, __syncthreads
// drains vmcnt) or a ~32-entry L1 MSHR cap. This version:
//  - 512-thr blocks, B-chunks <= 48 KB: L0/L2 have ZERO mid-kernel barriers,
//    L1 exactly one. Gather batches of 12 fenced loads drain progressively
//    (vmcnt(N)) through the MFMA phase; next batch issues immediately.
//  - __launch_bounds__(512,4): VGPR cap 128 (need ~110) -> 2 blocks/CU,
//    16 waves/CU, LDS 96 KB/CU.
//  - A-gathers use __builtin_nontemporal_load (nt): h has no L1 reuse; tests
//    whether nt lifts the L1 MSHR cap.

typedef __bf16 bf16;
typedef bf16  bf16x4 __attribute__((ext_vector_type(4)));
typedef bf16  bf16x8 __attribute__((ext_vector_type(8)));
typedef float f32x4  __attribute__((ext_vector_type(4)));

// Pack W [K][COUT] f32 into fragment-ordered bf16:
// frag f = (s*CC + cc)*NT + t; element lane*8+j of frag f is
// W[k = s*CIN + cc*32 + (lane>>4)*8 + j][col = t*16 + (lane&15)].
template<int CIN, int COUT>
__device__ inline void pack_one(const float* __restrict__ W, bf16* __restrict__ BP, int e) {
    constexpr int NT = COUT / 16, CC = CIN / 32;
    const int f = e >> 9, r = e & 511, lane = r >> 3, j = r & 7;
    const int t = f % NT, cc = (f / NT) % CC, s = f / (NT * CC);
    const int col = t * 16 + (lane & 15);
    const int k   = s * CIN + cc * 32 + (lane >> 4) * 8 + j;
    BP[e] = (bf16)W[k * COUT + col];
}

__global__ __launch_bounds__(256)
void prep_all(const float* __restrict__ x, bf16* __restrict__ xb,
              const float* __restrict__ W0, const float* __restrict__ W1,
              const float* __restrict__ W2, bf16* __restrict__ B0,
              bf16* __restrict__ B1, bf16* __restrict__ B2, int n)
{
    const int gid = blockIdx.x * 256 + threadIdx.x;
    const int e = gid * 4;
    if (e < n * 32) {
        const f32x4 v = *reinterpret_cast<const f32x4*>(x + e);
        bf16x4 o = {(bf16)v[0], (bf16)v[1], (bf16)v[2], (bf16)v[3]};
        *reinterpret_cast<bf16x4*>(xb + e) = o;
    }
    if (gid < 384 * 64)                       pack_one<32, 64>(W0, B0, gid);
    else if (gid < 384 * 64 + 768 * 64)       pack_one<64, 64>(W1, B1, gid - 384 * 64);
    else if (gid < 384 * 64 + 768 * 64 + 768 * 32)
                                              pack_one<64, 32>(W2, B2, gid - 384 * 64 - 768 * 64);
}

template<int CIN, int COUT, bool ELU, typename TOUT>
__global__ __launch_bounds__(512, 4)
void spiral_mfma(const bf16* __restrict__ h, const int* __restrict__ idx,
                 const bf16* __restrict__ BP, const float* __restrict__ bias,
                 TOUT* __restrict__ out, int n)
{
    constexpr int CC    = CIN / 32;       // 32-k chunks per step (1 or 2)
    constexpr int NT    = COUT / 16;      // 16-col output tiles (4,4,2)
    constexpr int PS    = CIN * COUT;     // B elems per step (2048,4096,2048)
    constexpr int CHS   = (24576 / PS < 12) ? (24576 / PS) : 12; // steps/LDS-chunk
    constexpr int NCH   = 12 / CHS;       // LDS chunks (1,2,1)
    constexpr int BSTEP = 12 / CC;        // steps per gather batch (12 or 6)
    constexpr int NB    = CHS / BSTEP;    // batches per chunk (1,1,2)

    __shared__ bf16 Bs[CHS * PS];         // 48 KB always

    const int tid  = threadIdx.x;
    const int lane = tid & 63;
    const int wave = tid >> 6;            // 0..7
    const int m    = lane & 15;
    const int quad = lane >> 4;
    const int i0   = (blockIdx.x * 8 + wave) * 16;   // MR=1: 16 rows/wave
    const bool valid = (i0 < n);                     // n%16==0: all-or-none

    // Gather indices (48B/row, 16B-aligned), clamped for tail waves.
    const int ir = min(i0 + m, n - 1);
    const int4* ip = reinterpret_cast<const int4*>(idx + (size_t)ir * 12);
    const int4 q0 = ip[0], q1 = ip[1], q2 = ip[2];
    const int rg[12] = {q0.x,q0.y,q0.z,q0.w, q1.x,q1.y,q1.z,q1.w, q2.x,q2.y,q2.z,q2.w};

    f32x4 acc[NT] = {};

    #pragma unroll
    for (int c = 0; c < NCH; ++c) {
        if (c) __syncthreads();           // only L1 hits this (once)
        // Stage chunk c of packed B into LDS (contiguous 16B copies).
        const bf16* src = BP + (size_t)c * CHS * PS;
        #pragma unroll
        for (int r2 = tid; r2 < CHS * PS / 8; r2 += 512)
            *reinterpret_cast<bf16x8*>(&Bs[r2 * 8]) =
                *reinterpret_cast<const bf16x8*>(&src[r2 * 8]);
        __syncthreads();

        #pragma unroll
        for (int b = 0; b < NB; ++b) {
            // ---- 12 independent nt gathers, fenced ----
            bf16x8 a[12];
            #pragma unroll
            for (int sl = 0; sl < BSTEP; ++sl) {
                const int s = c * CHS + b * BSTEP + sl;
                #pragma unroll
                for (int cc = 0; cc < CC; ++cc)
                    a[sl * CC + cc] = __builtin_nontemporal_load(
                        reinterpret_cast<const bf16x8*>(
                            h + (size_t)rg[s] * CIN + cc * 32 + quad * 8));
            }
            __builtin_amdgcn_sched_barrier(0);   // all 12 issue before MFMAs
            // ---- MFMAs: progressive vmcnt drain in consumption order ----
            #pragma unroll
            for (int p = 0; p < 12; ++p) {
                const int fr = (b * BSTEP * CC + p) * NT;   // frag index in chunk
                #pragma unroll
                for (int t = 0; t < NT; ++t) {
                    const bf16x8 bb = *reinterpret_cast<const bf16x8*>(
                        &Bs[(fr + t) * 512 + lane * 8]);
                    acc[t] = __builtin_amdgcn_mfma_f32_16x16x32_bf16(a[p], bb, acc[t], 0, 0, 0);
                }
            }
        }
    }

    if (!valid) return;

    // Epilogue: D[row = quad*4+g][col = t*16+m]; n%16==0 -> no row guards.
    #pragma unroll
    for (int t = 0; t < NT; ++t) {
        const int col = t * 16 + m;
        const float bv = bias[col];
        #pragma unroll
        for (int g = 0; g < 4; ++g) {
            const int row = i0 + quad * 4 + g;
            float v = acc[t][g] + bv;
            if (ELU) v = (v > 0.f) ? v : (__expf(v) - 1.f);
            out[(size_t)row * COUT + col] = (TOUT)v;
        }
    }
}

extern "C" void kernel_launch(void* const* d_in, const int* in_sizes, int n_in,
                              void* d_out, int out_size, void* d_ws, size_t ws_size,
                              hipStream_t stream) {
    const float* x   = (const float*)d_in[0];   // [N,32] fp32
    const int*   idx = (const int*)d_in[1];     // [N,12]
    const float* W0  = (const float*)d_in[2];   // [384,64]
    const float* b0  = (const float*)d_in[3];
    const float* W1  = (const float*)d_in[4];   // [768,64]
    const float* b1  = (const float*)d_in[5];
    const float* W2  = (const float*)d_in[6];   // [768,32]
    const float* b2  = (const float*)d_in[7];
    float* out = (float*)d_out;                 // [N,32] fp32

    const int n = in_sizes[0] / 32;             // N = 100000

    bf16* xb = (bf16*)d_ws;                     // [n,32]
    bf16* h1 = xb + (size_t)n * 32;             // [n,64]
    bf16* h2 = h1 + (size_t)n * 64;             // [n,64]
    bf16* B0 = h2 + (size_t)n * 64;             // 384*64
    bf16* B1 = B0 + 384 * 64;                   // 768*64
    bf16* B2 = B1 + 768 * 64;                   // 768*32

    const int prep_threads = n * 8;             // covers n*32/4 cvt + 98304 pack
    prep_all<<<(prep_threads + 255) / 256, dim3(256), 0, stream>>>(x, xb, W0, W1, W2, B0, B1, B2, n);

    const int grid = (n + 127) / 128;           // 8 waves x 16 rows per block
    spiral_mfma<32, 64, true,  bf16 ><<<grid, dim3(512), 0, stream>>>(xb, idx, B0, b0, h1,  n);
    spiral_mfma<64, 64, true,  bf16 ><<<grid, dim3(512), 0, stream>>>(h1, idx, B1, b1, h2,  n);
    spiral_mfma<64, 32, false, float><<<grid, dim3(512), 0, stream>>>(h2, idx, B2, b2, out, n);
}

// Round 10
// 158.278 us; speedup vs baseline: 1.2558x; 1.2558x over previous
//
#include <hip/hip_runtime.h>
#include <math.h>

// SpiralNet bf16-MFMA v10 = R8 (best, 158us) + gather duty-cycle pipeline.
// R9 lesson: nt loads bypass L2 -> regression; reverted. R10: double-buffered
// depth-6 gather batches -- batch for chunk c+1 issues right after chunk c's
// post-stage barrier and flies through the whole MFMA phase; batch 0 issues
// before the first B-staging (covered by staging latency). Pipe never restarts
// cold except at the per-chunk barrier drain, which now overlaps useful flight.
//  - block=256, MR=1 (16 rows/wave), grid 1563 ~ 6.1 blocks/CU.
//  - __launch_bounds__(256,5): 5 blocks/CU = 20 waves/CU; LDS 5 x <=24KB <= 120KB.
//  - Uniform batch depth 6 (SC=6/CC): a[2][6] = 48 VGPR for frags, cap 102.

typedef __bf16 bf16;
typedef bf16  bf16x4 __attribute__((ext_vector_type(4)));
typedef bf16  bf16x8 __attribute__((ext_vector_type(8)));
typedef float f32x4  __attribute__((ext_vector_type(4)));

// Pack W [K][COUT] f32 into fragment-ordered bf16:
// frag f = (s*CC + cc)*NT + t; element lane*8+j of frag f is
// W[k = s*CIN + cc*32 + (lane>>4)*8 + j][col = t*16 + (lane&15)].
template<int CIN, int COUT>
__device__ inline void pack_one(const float* __restrict__ W, bf16* __restrict__ BP, int e) {
    constexpr int NT = COUT / 16, CC = CIN / 32;
    const int f = e >> 9, r = e & 511, lane = r >> 3, j = r & 7;
    const int t = f % NT, cc = (f / NT) % CC, s = f / (NT * CC);
    const int col = t * 16 + (lane & 15);
    const int k   = s * CIN + cc * 32 + (lane >> 4) * 8 + j;
    BP[e] = (bf16)W[k * COUT + col];
}

__global__ __launch_bounds__(256)
void prep_all(const float* __restrict__ x, bf16* __restrict__ xb,
              const float* __restrict__ W0, const float* __restrict__ W1,
              const float* __restrict__ W2, bf16* __restrict__ B0,
              bf16* __restrict__ B1, bf16* __restrict__ B2, int n)
{
    const int gid = blockIdx.x * 256 + threadIdx.x;
    const int e = gid * 4;
    if (e < n * 32) {
        const f32x4 v = *reinterpret_cast<const f32x4*>(x + e);
        bf16x4 o = {(bf16)v[0], (bf16)v[1], (bf16)v[2], (bf16)v[3]};
        *reinterpret_cast<bf16x4*>(xb + e) = o;
    }
    if (gid < 384 * 64)                       pack_one<32, 64>(W0, B0, gid);
    else if (gid < 384 * 64 + 768 * 64)       pack_one<64, 64>(W1, B1, gid - 384 * 64);
    else if (gid < 384 * 64 + 768 * 64 + 768 * 32)
                                              pack_one<64, 32>(W2, B2, gid - 384 * 64 - 768 * 64);
}

template<int CIN, int COUT, bool ELU, typename TOUT>
__global__ __launch_bounds__(256, 5)
void spiral_mfma(const bf16* __restrict__ h, const int* __restrict__ idx,
                 const bf16* __restrict__ BP, const float* __restrict__ bias,
                 TOUT* __restrict__ out, int n)
{
    constexpr int CC  = CIN / 32;        // 32-k chunks per step (1 or 2)
    constexpr int NT  = COUT / 16;       // 16-col output tiles (4,4,2)
    constexpr int PS  = CIN * COUT;      // B elems per step
    constexpr int SC  = 6 / CC;          // steps per chunk -> depth SC*CC = 6
    constexpr int NCH = 12 / SC;         // chunks (2 for L0, 4 for L1/L2)
    constexpr int PL  = 6;               // gathers per batch

    __shared__ bf16 Bs[SC * PS];         // 24 KB (L0/L1), 12 KB (L2)

    const int tid  = threadIdx.x;
    const int lane = tid & 63;
    const int wave = tid >> 6;           // 0..3
    const int m    = lane & 15;
    const int quad = lane >> 4;
    const int i0   = (blockIdx.x * 4 + wave) * 16;   // MR=1: 16 rows/wave
    const bool valid = (i0 < n);                     // n%16==0: all-or-none

    // Gather indices (48B/row, 16B-aligned), clamped for tail waves.
    const int ir = min(i0 + m, n - 1);
    const int4* ip = reinterpret_cast<const int4*>(idx + (size_t)ir * 12);
    const int4 q0 = ip[0], q1 = ip[1], q2 = ip[2];
    const int rg[12] = {q0.x,q0.y,q0.z,q0.w, q1.x,q1.y,q1.z,q1.w, q2.x,q2.y,q2.z,q2.w};

    f32x4 acc[NT] = {};
    bf16x8 A[2][PL];                     // double-buffered gather batches

    // Issue batch 0 BEFORE any staging: covered by staging latency.
    #pragma unroll
    for (int sl = 0; sl < SC; ++sl)
        #pragma unroll
        for (int cc = 0; cc < CC; ++cc)
            A[0][sl * CC + cc] = *reinterpret_cast<const bf16x8*>(
                h + (size_t)rg[sl] * CIN + cc * 32 + quad * 8);

    #pragma unroll
    for (int c = 0; c < NCH; ++c) {
        if (c) __syncthreads();          // Bs reuse (drains vmem incl. in-flight
                                         // batch -- overlapped useful flight)
        // Stage chunk c of packed B into LDS (contiguous 16B copies).
        const bf16* src = BP + (size_t)c * SC * PS;
        #pragma unroll
        for (int r2 = tid; r2 < SC * PS / 8; r2 += 256)
            *reinterpret_cast<bf16x8*>(&Bs[r2 * 8]) =
                *reinterpret_cast<const bf16x8*>(&src[r2 * 8]);
        __syncthreads();

        // Issue NEXT chunk's batch: flies through this chunk's MFMA phase.
        if (c + 1 < NCH) {
            #pragma unroll
            for (int sl = 0; sl < SC; ++sl)
                #pragma unroll
                for (int cc = 0; cc < CC; ++cc)
                    A[(c + 1) & 1][sl * CC + cc] = *reinterpret_cast<const bf16x8*>(
                        h + (size_t)rg[(c + 1) * SC + sl] * CIN + cc * 32 + quad * 8);
        }

        // Consume current batch: 6*NT MFMAs, B from LDS (lgkmcnt domain).
        #pragma unroll
        for (int p = 0; p < PL; ++p)
            #pragma unroll
            for (int t = 0; t < NT; ++t) {
                const bf16x8 b = *reinterpret_cast<const bf16x8*>(
                    &Bs[(p * NT + t) * 512 + lane * 8]);
                acc[t] = __builtin_amdgcn_mfma_f32_16x16x32_bf16(A[c & 1][p], b, acc[t], 0, 0, 0);
            }
    }

    if (!valid) return;

    // Epilogue: D[row = quad*4+g][col = t*16+m]; n%16==0 -> no row guards.
    #pragma unroll
    for (int t = 0; t < NT; ++t) {
        const int col = t * 16 + m;
        const float bv = bias[col];
        #pragma unroll
        for (int g = 0; g < 4; ++g) {
            const int row = i0 + quad * 4 + g;
            float v = acc[t][g] + bv;
            if (ELU) v = (v > 0.f) ? v : (__expf(v) - 1.f);
            out[(size_t)row * COUT + col] = (TOUT)v;
        }
    }
}

extern "C" void kernel_launch(void* const* d_in, const int* in_sizes, int n_in,
                              void* d_out, int out_size, void* d_ws, size_t ws_size,
                              hipStream_t stream) {
    const float* x   = (const float*)d_in[0];   // [N,32] fp32
    const int*   idx = (const int*)d_in[1];     // [N,12]
    const float* W0  = (const float*)d_in[2];   // [384,64]
    const float* b0  = (const float*)d_in[3];
    const float* W1  = (const float*)d_in[4];   // [768,64]
    const float* b1  = (const float*)d_in[5];
    const float* W2  = (const float*)d_in[6];   // [768,32]
    const float* b2  = (const float*)d_in[7];
    float* out = (float*)d_out;                 // [N,32] fp32

    const int n = in_sizes[0] / 32;             // N = 100000

    bf16* xb = (bf16*)d_ws;                     // [n,32]
    bf16* h1 = xb + (size_t)n * 32;             // [n,64]
    bf16* h2 = h1 + (size_t)n * 64;             // [n,64]
    bf16* B0 = h2 + (size_t)n * 64;             // 384*64
    bf16* B1 = B0 + 384 * 64;                   // 768*64
    bf16* B2 = B1 + 768 * 64;                   // 768*32

    const int prep_threads = n * 8;             // covers n*32/4 cvt + 98304 pack
    prep_all<<<(prep_threads + 255) / 256, dim3(256), 0, stream>>>(x, xb, W0, W1, W2, B0, B1, B2, n);

    const int grid = (n + 63) / 64;             // 4 waves x 16 rows per block
    spiral_mfma<32, 64, true,  bf16 ><<<grid, dim3(256), 0, stream>>>(xb, idx, B0, b0, h1,  n);
    spiral_mfma<64, 64, true,  bf16 ><<<grid, dim3(256), 0, stream>>>(h1, idx, B1, b1, h2,  n);
    spiral_mfma<64, 32, false, float><<<grid, dim3(256), 0, stream>>>(h2, idx, B2, b2, out, n);
}